// Round 4
// baseline (207.611 us; speedup 1.0000x reference)
//
#include <hip/hip_runtime.h>

// LePEAttention idx=0 on MI355X — R11.
// R10 (XCD-sibling swizzle) confirmed at 99.3 us bench; with 2x ~42us poison fills per
// iteration the attn kernel is ~13-15 us vs 10.6 us HBM floor (67 MB unique). Residual
// = staging-latency exposure: monolithic 256-key stages stall on L3-cold loads (~900cy)
// with no compute to hide under. R11 = T14 pipeline: 4x128-key half-stages, double-
// buffered LDS (Ks 2x8KB + Vt 2x8.5KB = 33KB, still 4 blk/CU); per half-stage: issue
// next loads (32 f32 regs) -> compute current (4 tiles ~2000cy covers latency) ->
// cvt+ds_write -> barrier. Math/rounding identical to R10; V pitch 68 dwords/buffer
// (bank-perfect frag reads). Everything else (in-reg softmax via swapped 32x32x16
// QK^T + cvt_pk + permlane32_swap, sibling swizzle, epilogue) unchanged.
// qkv f32 [3,8,4096,128]; out f32 [8,4096,128]. 1024 blocks x 256 thr (4 waves).

typedef __attribute__((ext_vector_type(8)))  short bf16x8;
typedef __attribute__((ext_vector_type(4)))  float f32x4;
typedef __attribute__((ext_vector_type(16))) float f32x16;
typedef __attribute__((ext_vector_type(4)))  int   i32x4;

#define MFMA32(a, b, c) __builtin_amdgcn_mfma_f32_32x32x16_bf16(a, b, c, 0, 0, 0)

__device__ __forceinline__ unsigned cvtpk(float lo, float hi) {
    unsigned r;
    asm("v_cvt_pk_bf16_f32 %0, %1, %2" : "=v"(r) : "v"(lo), "v"(hi));
    return r;
}
// v_permlane32_swap_b32 vdst, vsrc:  dst' = {dst[0:31], src[0:31]}, src' = {dst[32:63], src[32:63]}
__device__ __forceinline__ void plswap(unsigned& a, unsigned& b) {
    asm("v_permlane32_swap_b32 %0, %1" : "+v"(a), "+v"(b));
}

__global__ __launch_bounds__(256, 4)
void lepe_attn_r11(const float* __restrict__ qkv, float* __restrict__ out)
{
    __shared__ __align__(16) short    Ks[2][128 * 32];  // 2 x 8 KB, XOR-swizzled 16B blocks
    __shared__ __align__(16) unsigned Vt[2][32 * 68];   // 2 x 8.5 KB: bf16 [dim][136] pitch, key pairs packed

    const int tid  = threadIdx.x;
    const int lane = tid & 63;
    const int m31  = lane & 31;
    const int hi   = lane >> 5;

    // ---- XCD-sibling swizzle: idx = (p&7) + 8*(4*(p>>3)+qsp)
    const int idx  = blockIdx.x;
    const int low3 = idx & 7;
    const int t5   = idx >> 3;
    const int qsp  = t5 & 3;
    const int pair = ((t5 >> 2) << 3) | low3;
    const int wi   = pair >> 2;
    const int hd   = pair & 3;
    const int b    = wi >> 3;
    const int wb   = wi & 7;
    const int chead = hd * 32;

    const size_t baseQ = (size_t)b * 524288;
    const size_t baseK = baseQ + 8u * 524288;
    const size_t baseV = baseQ + 16u * 524288;

    // ---- Q B-frags (B[n=q=lane&31][k=d=hi*8+j]), prescaled by SCALE*log2e
    const int wave = tid >> 6;
    const int q0w  = qsp * 128 + wave * 32;
    const float QS = 0.17677669529663687f * 1.4426950408889634f;
    bf16x8 qf0, qf1;
    {
        int qg = q0w + m31;
        int lq = (qg >> 3) * 64 + wb * 8 + (qg & 7);
        const float* qp = qkv + baseQ + (size_t)lq * 128 + chead + hi * 8;
        f32x4 qa = *(const f32x4*)qp;
        f32x4 qb = *(const f32x4*)(qp + 4);
        f32x4 qc = *(const f32x4*)(qp + 16);
        f32x4 qd = *(const f32x4*)(qp + 20);
        i32x4 w0, w1;
        w0[0] = cvtpk(qa[0] * QS, qa[1] * QS);
        w0[1] = cvtpk(qa[2] * QS, qa[3] * QS);
        w0[2] = cvtpk(qb[0] * QS, qb[1] * QS);
        w0[3] = cvtpk(qb[2] * QS, qb[3] * QS);
        w1[0] = cvtpk(qc[0] * QS, qc[1] * QS);
        w1[1] = cvtpk(qc[2] * QS, qc[3] * QS);
        w1[2] = cvtpk(qd[0] * QS, qd[1] * QS);
        w1[3] = cvtpk(qd[2] * QS, qd[3] * QS);
        qf0 = __builtin_bit_cast(bf16x8, w0);
        qf1 = __builtin_bit_cast(bf16x8, w1);
    }

    // ---- staging partitions (fixed per thread)
    const int krow  = tid >> 1;          // K: local key row 0..127
    const int khalf = tid & 1;           // K: 16-dim half
    const int vp    = tid & 63;          // V: key pair 0..63
    const int vqd   = tid >> 6;          // V: dim quarter 0..3

    f32x4 kr0, kr1, kr2, kr3;            // pipeline regs: K raw f32 (16)
    f32x4 vr0, vr1, vr2, vr3;            // pipeline regs: V raw f32 (16)

#define ISSUE_LOADS(h)                                                              \
    {                                                                               \
        int gk = (h) * 128 + krow;                                                  \
        int lk = (gk >> 3) * 64 + wb * 8 + (gk & 7);                                \
        const float* kp = qkv + baseK + (size_t)lk * 128 + chead + khalf * 16;      \
        kr0 = *(const f32x4*)kp;       kr1 = *(const f32x4*)(kp + 4);               \
        kr2 = *(const f32x4*)(kp + 8); kr3 = *(const f32x4*)(kp + 12);              \
        int k0g = (h) * 128 + 2 * vp;                                               \
        int l0  = (k0g >> 3) * 64 + wb * 8 + (k0g & 7);                             \
        const float* va = qkv + baseV + (size_t)l0 * 128 + chead + vqd * 8;         \
        vr0 = *(const f32x4*)va;         vr1 = *(const f32x4*)(va + 4);             \
        vr2 = *(const f32x4*)(va + 128); vr3 = *(const f32x4*)(va + 132);           \
    }

#define WRITE_LDS(buf)                                                              \
    {                                                                               \
        i32x4 ka, kb_;                                                              \
        ka[0]  = cvtpk(kr0[0], kr0[1]); ka[1]  = cvtpk(kr0[2], kr0[3]);             \
        ka[2]  = cvtpk(kr1[0], kr1[1]); ka[3]  = cvtpk(kr1[2], kr1[3]);             \
        kb_[0] = cvtpk(kr2[0], kr2[1]); kb_[1] = cvtpk(kr2[2], kr2[3]);             \
        kb_[2] = cvtpk(kr3[0], kr3[1]); kb_[3] = cvtpk(kr3[2], kr3[3]);             \
        int swz = (krow >> 1) & 3;                                                  \
        int j0  = khalf * 2;                                                        \
        *(i32x4*)&Ks[buf][krow * 32 + ((j0 ^ swz) << 3)]       = ka;                \
        *(i32x4*)&Ks[buf][krow * 32 + (((j0 + 1) ^ swz) << 3)] = kb_;               \
        _Pragma("unroll")                                                           \
        for (int e = 0; e < 4; ++e) {                                               \
            Vt[buf][(vqd * 8 + e) * 68 + vp]     = cvtpk(vr0[e], vr2[e]);           \
            Vt[buf][(vqd * 8 + 4 + e) * 68 + vp] = cvtpk(vr1[e], vr3[e]);           \
        }                                                                           \
    }

    f32x16 o = (f32x16)0.0f;   // O[q=crow(r,hi)][d=lane&31]
    float lsum = 0.0f;

    // ---- prologue: stage half-stage 0 (only exposed-latency stage)
    ISSUE_LOADS(0);
    WRITE_LDS(0);
    __syncthreads();

#pragma unroll
    for (int hs = 0; hs < 4; ++hs) {
        const int cur = hs & 1;
        if (hs < 3) ISSUE_LOADS(hs + 1);              // fly under compute

        const short* KsB = &Ks[cur][0];
        const short* VtB = (const short*)&Vt[cur][0];
#pragma unroll
        for (int kb = 0; kb < 128; kb += 32) {
            int row0 = kb + m31;
            int swz  = (row0 >> 1) & 3;
            bf16x8 kfa = *(const bf16x8*)&KsB[row0 * 32 + (((0 + hi) ^ swz) << 3)];  // d  0..15
            bf16x8 kfb = *(const bf16x8*)&KsB[row0 * 32 + (((2 + hi) ^ swz) << 3)];  // d 16..31
            bf16x8 vf0 = *(const bf16x8*)&VtB[m31 * 136 + kb + hi * 8];        // keys kb+0..15
            bf16x8 vf1 = *(const bf16x8*)&VtB[m31 * 136 + kb + 16 + hi * 8];   // keys kb+16..31

            // Swapped QK^T: S[key=crow(r,hi)][q=m31]
            f32x16 s = MFMA32(kfa, qf0, (f32x16)0.0f);
            s = MFMA32(kfb, qf1, s);

            float p[16];
#pragma unroll
            for (int r = 0; r < 16; ++r) p[r] = __builtin_amdgcn_exp2f(s[r]);

            float t01 = p[0] + p[1],   t23 = p[2] + p[3];
            float t45 = p[4] + p[5],   t67 = p[6] + p[7];
            float t89 = p[8] + p[9],   tab = p[10] + p[11];
            float tcd = p[12] + p[13], tef = p[14] + p[15];
            lsum += ((t01 + t23) + (t45 + t67)) + ((t89 + tab) + (tcd + tef));

            unsigned c0 = cvtpk(p[0], p[1]);
            unsigned c1 = cvtpk(p[2], p[3]);
            unsigned c2 = cvtpk(p[4], p[5]);
            unsigned c3 = cvtpk(p[6], p[7]);
            plswap(c0, c2);
            plswap(c1, c3);
            i32x4 pw0; pw0[0] = c0; pw0[1] = c1; pw0[2] = c2; pw0[3] = c3;

            unsigned c4 = cvtpk(p[8], p[9]);
            unsigned c5 = cvtpk(p[10], p[11]);
            unsigned c6 = cvtpk(p[12], p[13]);
            unsigned c7 = cvtpk(p[14], p[15]);
            plswap(c4, c6);
            plswap(c5, c7);
            i32x4 pw1; pw1[0] = c4; pw1[1] = c5; pw1[2] = c6; pw1[3] = c7;

            o = MFMA32(__builtin_bit_cast(bf16x8, pw0), vf0, o);
            o = MFMA32(__builtin_bit_cast(bf16x8, pw1), vf1, o);
        }

        if (hs < 3) {
            WRITE_LDS((hs + 1) & 1);                  // cvt + ds_write the prefetched tile
            __syncthreads();
        }
    }

    // ---- epilogue: combine half-sums across lane^32, normalize, store f32
    float ls  = lsum + __shfl_xor(lsum, 32);
    float inv = 1.0f / ls;
    const size_t baseO = (size_t)b * 524288;
#pragma unroll
    for (int r = 0; r < 16; ++r) {
        int qw = (r & 3) + 8 * (r >> 2) + 4 * hi;     // local q row of o[r]
        float iv = __shfl(inv, qw);
        int q  = q0w + qw;
        int lq = (q >> 3) * 64 + wb * 8 + (q & 7);
        out[baseO + (size_t)lq * 128 + chead + m31] = o[r] * iv;
    }
#undef ISSUE_LOADS
#undef WRITE_LDS
}

extern "C" void kernel_launch(void* const* d_in, const int* in_sizes, int n_in,
                              void* d_out, int out_size, void* d_ws, size_t ws_size,
                              hipStream_t stream) {
    const float* qkv = (const float*)d_in[0];
    float* out = (float*)d_out;
    lepe_attn_r11<<<dim3(1024), dim3(256), 0, stream>>>(qkv, out);
}

// Round 5
// 107.366 us; speedup vs baseline: 1.9337x; 1.9337x over previous
//
#include <hip/hip_runtime.h>

// LePEAttention idx=0 on MI355X — R12.
// R11 (128-key half-stage pipeline, 32 prefetch VGPRs) SPILLED: VGPR_Count=64 (arch/
// AGPR split under the 128 budget), WRITE_SIZE 219 MB/dispatch = scratch traffic,
// kernel 148 us. The pipeline idea stands; the register cost killed it. R12 keeps the
// T14 pipeline but: 64-key quarter-stages (8 stages), prefetch = 16 VGPRs (K 2xf32x4 +
// V 2xf32x4), liveness = ONE 32-key tile (ISSUE -> tile0 -> WRITE -> tile1 -> barrier),
// unroll 2 only. LDS: Ks 2x4KB + Vt 2x4.5KB (pitch 36 dwords) = 17 KB, 4 blk/CU.
// Math/swizzles/in-reg softmax (swapped 32x32x16 QK^T + cvt_pk + permlane32_swap),
// XCD-sibling swizzle, epilogue identical to R10 (99.3 us bench, kernel ~14 us vs
// 10.6 us HBM floor). qkv f32 [3,8,4096,128]; out f32 [8,4096,128]. 1024 x 256 thr.

typedef __attribute__((ext_vector_type(8)))  short bf16x8;
typedef __attribute__((ext_vector_type(4)))  float f32x4;
typedef __attribute__((ext_vector_type(16))) float f32x16;
typedef __attribute__((ext_vector_type(4)))  int   i32x4;

#define MFMA32(a, b, c) __builtin_amdgcn_mfma_f32_32x32x16_bf16(a, b, c, 0, 0, 0)

__device__ __forceinline__ unsigned cvtpk(float lo, float hi) {
    unsigned r;
    asm("v_cvt_pk_bf16_f32 %0, %1, %2" : "=v"(r) : "v"(lo), "v"(hi));
    return r;
}
// v_permlane32_swap_b32 vdst, vsrc:  dst' = {dst[0:31], src[0:31]}, src' = {dst[32:63], src[32:63]}
__device__ __forceinline__ void plswap(unsigned& a, unsigned& b) {
    asm("v_permlane32_swap_b32 %0, %1" : "+v"(a), "+v"(b));
}

__global__ __launch_bounds__(256, 4)
void lepe_attn_r12(const float* __restrict__ qkv, float* __restrict__ out)
{
    __shared__ __align__(16) short    Ks[2][64 * 32];   // 2 x 4 KB, XOR-swizzled 16B parts
    __shared__ __align__(16) unsigned Vt[2][32 * 36];   // 2 x 4.5 KB: [dim][pitch 36 dw], key pairs packed

    const int tid  = threadIdx.x;
    const int lane = tid & 63;
    const int m31  = lane & 31;
    const int hi   = lane >> 5;

    // ---- XCD-sibling swizzle: idx = (p&7) + 8*(4*(p>>3)+qsp)
    const int idx  = blockIdx.x;
    const int low3 = idx & 7;
    const int t5   = idx >> 3;
    const int qsp  = t5 & 3;
    const int pair = ((t5 >> 2) << 3) | low3;
    const int wi   = pair >> 2;
    const int hd   = pair & 3;
    const int b    = wi >> 3;
    const int wb   = wi & 7;
    const int chead = hd * 32;

    const size_t baseQ = (size_t)b * 524288;
    const size_t baseK = baseQ + 8u * 524288;
    const size_t baseV = baseQ + 16u * 524288;

    // ---- Q B-frags (B[n=q=lane&31][k=d=hi*8+j]), prescaled by SCALE*log2e
    const int wave = tid >> 6;
    const int q0w  = qsp * 128 + wave * 32;
    const float QS = 0.17677669529663687f * 1.4426950408889634f;
    bf16x8 qf0, qf1;
    {
        int qg = q0w + m31;
        int lq = (qg >> 3) * 64 + wb * 8 + (qg & 7);
        const float* qp = qkv + baseQ + (size_t)lq * 128 + chead + hi * 8;
        f32x4 qa = *(const f32x4*)qp;
        f32x4 qb = *(const f32x4*)(qp + 4);
        f32x4 qc = *(const f32x4*)(qp + 16);
        f32x4 qd = *(const f32x4*)(qp + 20);
        i32x4 w0, w1;
        w0[0] = cvtpk(qa[0] * QS, qa[1] * QS);
        w0[1] = cvtpk(qa[2] * QS, qa[3] * QS);
        w0[2] = cvtpk(qb[0] * QS, qb[1] * QS);
        w0[3] = cvtpk(qb[2] * QS, qb[3] * QS);
        w1[0] = cvtpk(qc[0] * QS, qc[1] * QS);
        w1[1] = cvtpk(qc[2] * QS, qc[3] * QS);
        w1[2] = cvtpk(qd[0] * QS, qd[1] * QS);
        w1[3] = cvtpk(qd[2] * QS, qd[3] * QS);
        qf0 = __builtin_bit_cast(bf16x8, w0);
        qf1 = __builtin_bit_cast(bf16x8, w1);
    }

    // ---- staging partitions (fixed per thread)
    const int krow  = tid & 63;          // K: local key row 0..63
    const int khalf = tid >> 6;          // K: 16B dim-part 0..3 (dims khalf*8..+7)
    const int vpp   = tid & 31;          // V: key pair 0..31
    const int vdq   = tid >> 5;          // V: dim quad 0..7 (dims vdq*4..+3)

    f32x4 kr0, kr1, vr0, vr1;            // 16 prefetch VGPRs

#define ISSUE(h)                                                                    \
    {                                                                               \
        int gk = (h) * 64 + krow;                                                   \
        int lk = (gk >> 3) * 64 + wb * 8 + (gk & 7);                                \
        const float* kp = qkv + baseK + (size_t)lk * 128 + chead + khalf * 8;       \
        kr0 = *(const f32x4*)kp;                                                    \
        kr1 = *(const f32x4*)(kp + 4);                                              \
        int k0g = (h) * 64 + 2 * vpp;                                               \
        int l0  = (k0g >> 3) * 64 + wb * 8 + (k0g & 7);                             \
        const float* vp_ = qkv + baseV + (size_t)l0 * 128 + chead + vdq * 4;        \
        vr0 = *(const f32x4*)vp_;                                                   \
        vr1 = *(const f32x4*)(vp_ + 128);                                           \
    }

#define WRITE(buf)                                                                  \
    {                                                                               \
        i32x4 kd;                                                                   \
        kd[0] = cvtpk(kr0[0], kr0[1]); kd[1] = cvtpk(kr0[2], kr0[3]);               \
        kd[2] = cvtpk(kr1[0], kr1[1]); kd[3] = cvtpk(kr1[2], kr1[3]);               \
        *(i32x4*)&Ks[buf][krow * 32 + ((khalf ^ ((krow >> 1) & 3)) << 3)] = kd;     \
        _Pragma("unroll")                                                           \
        for (int e = 0; e < 4; ++e)                                                 \
            Vt[buf][(vdq * 4 + e) * 36 + vpp] = cvtpk(vr0[e], vr1[e]);              \
    }

#define TILE(KB)                                                                    \
    {                                                                               \
        int row0 = (KB) + m31;                                                      \
        int swz  = (row0 >> 1) & 3;                                                 \
        bf16x8 kfa = *(const bf16x8*)&KsB[row0 * 32 + (((0 + hi) ^ swz) << 3)];     \
        bf16x8 kfb = *(const bf16x8*)&KsB[row0 * 32 + (((2 + hi) ^ swz) << 3)];     \
        bf16x8 vf0 = *(const bf16x8*)&VtB[m31 * 72 + (KB) + hi * 8];                \
        bf16x8 vf1 = *(const bf16x8*)&VtB[m31 * 72 + (KB) + 16 + hi * 8];           \
        f32x16 s = MFMA32(kfa, qf0, (f32x16)0.0f);                                  \
        s = MFMA32(kfb, qf1, s);                                                    \
        float p[16];                                                                \
        _Pragma("unroll")                                                           \
        for (int r = 0; r < 16; ++r) p[r] = __builtin_amdgcn_exp2f(s[r]);           \
        float t01 = p[0] + p[1],   t23 = p[2] + p[3];                               \
        float t45 = p[4] + p[5],   t67 = p[6] + p[7];                               \
        float t89 = p[8] + p[9],   tab = p[10] + p[11];                             \
        float tcd = p[12] + p[13], tef = p[14] + p[15];                             \
        lsum += ((t01 + t23) + (t45 + t67)) + ((t89 + tab) + (tcd + tef));          \
        unsigned c0 = cvtpk(p[0], p[1]);                                            \
        unsigned c1 = cvtpk(p[2], p[3]);                                            \
        unsigned c2 = cvtpk(p[4], p[5]);                                            \
        unsigned c3 = cvtpk(p[6], p[7]);                                            \
        plswap(c0, c2);                                                             \
        plswap(c1, c3);                                                             \
        i32x4 pw0; pw0[0] = c0; pw0[1] = c1; pw0[2] = c2; pw0[3] = c3;              \
        unsigned c4 = cvtpk(p[8],  p[9]);                                           \
        unsigned c5 = cvtpk(p[10], p[11]);                                          \
        unsigned c6 = cvtpk(p[12], p[13]);                                          \
        unsigned c7 = cvtpk(p[14], p[15]);                                          \
        plswap(c4, c6);                                                             \
        plswap(c5, c7);                                                             \
        i32x4 pw1; pw1[0] = c4; pw1[1] = c5; pw1[2] = c6; pw1[3] = c7;              \
        o = MFMA32(__builtin_bit_cast(bf16x8, pw0), vf0, o);                        \
        o = MFMA32(__builtin_bit_cast(bf16x8, pw1), vf1, o);                        \
    }

    f32x16 o = (f32x16)0.0f;   // O[q=crow(r,hi)][d=lane&31]
    float lsum = 0.0f;

    // ---- prologue: stage quarter 0 (only exposed-latency stage)
    ISSUE(0);
    WRITE(0);
    __syncthreads();

#pragma unroll 2
    for (int hs = 0; hs < 8; ++hs) {
        const int cur = hs & 1;
        const short* KsB = &Ks[cur][0];
        const short* VtB = (const short*)&Vt[cur][0];
        if (hs < 7) ISSUE(hs + 1);       // loads fly under tile0
        TILE(0);
        if (hs < 7) WRITE(cur ^ 1);      // cvt+ds_write; prefetch regs die here
        TILE(32);
        if (hs < 7) __syncthreads();
    }

    // ---- epilogue: combine half-sums across lane^32, normalize, store f32
    float ls  = lsum + __shfl_xor(lsum, 32);
    float inv = 1.0f / ls;
    const size_t baseO = (size_t)b * 524288;
#pragma unroll
    for (int r = 0; r < 16; ++r) {
        int qw = (r & 3) + 8 * (r >> 2) + 4 * hi;     // local q row of o[r]
        float iv = __shfl(inv, qw);
        int q  = q0w + qw;
        int lq = (q >> 3) * 64 + wb * 8 + (q & 7);
        out[baseO + (size_t)lq * 128 + chead + m31] = o[r] * iv;
    }
#undef ISSUE
#undef WRITE
#undef TILE
}

extern "C" void kernel_launch(void* const* d_in, const int* in_sizes, int n_in,
                              void* d_out, int out_size, void* d_ws, size_t ws_size,
                              hipStream_t stream) {
    const float* qkv = (const float*)d_in[0];
    float* out = (float*)d_out;
    lepe_attn_r12<<<dim3(1024), dim3(256), 0, stream>>>(qkv, out);
}

// Round 6
// 99.981 us; speedup vs baseline: 2.0765x; 1.0739x over previous
//
#include <hip/hip_runtime.h>

// LePEAttention idx=0 on MI355X — R13 (= R10 revert; best verified state).
// Session ledger: R8 in-reg softmax (swapped 32x32x16 QK^T + cvt_pk + permlane32_swap)
// 109->104; R9 mega-block traffic cut REGRESSED (-6, killed inter-block latency
// stagger); R10 XCD-sibling swizzle 104->99.3 (all 4 q-split siblings of a (win,head)
// pair on one XCD -> K/V slice HBM-fetched once, L2-hit 3x); R11 128-key pipeline
// SPILLED (VGPR 64 arch-split, 219 MB scratch, kernel 148us); R12 64-key pipeline
// REGRESSED (107.4: 8 barriers vs 3, vmcnt-draining WRITE between dependent tiles,
// 1-tile prefetch distance ~= L2 latency). Conclusion: at 4 blocks/CU the natural
// inter-block stagger covers staging latency better than any intra-block pipeline
// this register budget affords. Bench = ~84us harness poison-fills + ~15us kernel
// vs 10.6us HBM floor (67 MB unique @ 6.3 TB/s); remaining headroom <= 4us, both
// capture attempts lost more. This is the ship state.
// qkv f32 [3,8,4096,128]; out f32 [8,4096,128]. 64 windows of S=512, 256 pairs x 4
// q-splits(128q); block 256 = 4 waves x 32 q. LDS 32.5 KB, 4 blk/CU.

typedef __attribute__((ext_vector_type(8)))  short bf16x8;
typedef __attribute__((ext_vector_type(4)))  float f32x4;
typedef __attribute__((ext_vector_type(16))) float f32x16;
typedef __attribute__((ext_vector_type(4)))  int   i32x4;

#define MFMA32(a, b, c) __builtin_amdgcn_mfma_f32_32x32x16_bf16(a, b, c, 0, 0, 0)

__device__ __forceinline__ unsigned cvtpk(float lo, float hi) {
    unsigned r;
    asm("v_cvt_pk_bf16_f32 %0, %1, %2" : "=v"(r) : "v"(lo), "v"(hi));
    return r;
}
// v_permlane32_swap_b32 vdst, vsrc:  dst' = {dst[0:31], src[0:31]}, src' = {dst[32:63], src[32:63]}
__device__ __forceinline__ void plswap(unsigned& a, unsigned& b) {
    asm("v_permlane32_swap_b32 %0, %1" : "+v"(a), "+v"(b));
}

__global__ __launch_bounds__(256, 4)
void lepe_attn_r13(const float* __restrict__ qkv, float* __restrict__ out)
{
    __shared__ __align__(16) short    Ks[256 * 32];    // 16 KB, XOR-swizzled 16B blocks
    __shared__ __align__(16) unsigned Vt32[32 * 132];  // 16.5 KB: bf16 [dim][264] pitch, keys packed in pairs

    const int tid  = threadIdx.x;
    const int wave = tid >> 6;
    const int lane = tid & 63;
    const int m31  = lane & 31;
    const int hi   = lane >> 5;

    // ---- XCD-sibling swizzle: idx = (p&7) + 8*(4*(p>>3)+qsp)
    // All 4 q-splits of pair p share idx%8 -> same XCD, consecutive dispatch order.
    const int idx  = blockIdx.x;
    const int low3 = idx & 7;
    const int t5   = idx >> 3;
    const int qsp  = t5 & 3;
    const int pair = ((t5 >> 2) << 3) | low3;
    const int wi   = pair >> 2;
    const int hd   = pair & 3;
    const int b    = wi >> 3;
    const int wb   = wi & 7;
    const int chead = hd * 32;

    const size_t baseQ = (size_t)b * 524288;
    const size_t baseK = baseQ + 8u * 524288;
    const size_t baseV = baseQ + 16u * 524288;

    // ---- Q B-frags (B[n=q=lane&31][k=d=hi*8+j]), prescaled by SCALE*log2e
    const int q0w = qsp * 128 + wave * 32;
    const float QS = 0.17677669529663687f * 1.4426950408889634f;
    bf16x8 qf0, qf1;
    {
        int qg = q0w + m31;
        int lq = (qg >> 3) * 64 + wb * 8 + (qg & 7);
        const float* qp = qkv + baseQ + (size_t)lq * 128 + chead + hi * 8;
        f32x4 qa = *(const f32x4*)qp;          // dims hi*8 + 0..3
        f32x4 qb = *(const f32x4*)(qp + 4);    // dims hi*8 + 4..7
        f32x4 qc = *(const f32x4*)(qp + 16);   // dims 16 + hi*8 + 0..3
        f32x4 qd = *(const f32x4*)(qp + 20);   // dims 16 + hi*8 + 4..7
        i32x4 w0, w1;
        w0[0] = cvtpk(qa[0] * QS, qa[1] * QS);
        w0[1] = cvtpk(qa[2] * QS, qa[3] * QS);
        w0[2] = cvtpk(qb[0] * QS, qb[1] * QS);
        w0[3] = cvtpk(qb[2] * QS, qb[3] * QS);
        w1[0] = cvtpk(qc[0] * QS, qc[1] * QS);
        w1[1] = cvtpk(qc[2] * QS, qc[3] * QS);
        w1[2] = cvtpk(qd[0] * QS, qd[1] * QS);
        w1[3] = cvtpk(qd[2] * QS, qd[3] * QS);
        qf0 = __builtin_bit_cast(bf16x8, w0);
        qf1 = __builtin_bit_cast(bf16x8, w1);
    }

    f32x16 o = (f32x16)0.0f;   // O[q=crow(r,hi)][d=lane&31]
    float lsum = 0.0f;         // per-lane: sum of P[q=lane&31][its 256 keys]

    const short* Vts = (const short*)Vt32;

    for (int stage = 0; stage < 2; ++stage) {
        if (stage) __syncthreads();
        const int keybase = stage * 256;

        // ---- K staging: row-major bf16 [key][32 dims], XOR-swizzled 16B blocks
#pragma unroll
        for (int i = 0; i < 4; ++i) {
            int chunk = i * 256 + tid;
            int row   = chunk >> 2;              // local key
            int part  = chunk & 3;               // 16B dim-block
            int gk    = keybase + row;
            int lk    = (gk >> 3) * 64 + wb * 8 + (gk & 7);
            const float* kp = qkv + baseK + (size_t)lk * 128 + chead + part * 8;
            f32x4 k0 = *(const f32x4*)kp;
            f32x4 k1 = *(const f32x4*)(kp + 4);
            i32x4 kd;
            kd[0] = cvtpk(k0[0], k0[1]);
            kd[1] = cvtpk(k0[2], k0[3]);
            kd[2] = cvtpk(k1[0], k1[1]);
            kd[3] = cvtpk(k1[2], k1[3]);
            *(i32x4*)&Ks[row * 32 + ((part ^ ((row >> 1) & 3)) << 3)] = kd;
        }
        // ---- V staging: transposed bf16 [dim][key], pair-packed dwords
        {
            int p    = tid >> 1;                 // key pair 0..127
            int half = tid & 1;                  // dim half
            int k0g  = keybase + 2 * p;
            int l0   = (k0g >> 3) * 64 + wb * 8 + (k0g & 7);   // key 2p+1 is row l0+1
            const float* va = qkv + baseV + (size_t)l0 * 128 + chead + half * 16;
            const float* vb = va + 128;
            f32x4 a[4], bb[4];
#pragma unroll
            for (int j = 0; j < 4; ++j) { a[j] = *(const f32x4*)(va + 4 * j); bb[j] = *(const f32x4*)(vb + 4 * j); }
#pragma unroll
            for (int j = 0; j < 4; ++j)
#pragma unroll
                for (int e = 0; e < 4; ++e) {
                    int dim = half * 16 + j * 4 + e;
                    Vt32[dim * 132 + p] = cvtpk(a[j][e], bb[j][e]);
                }
        }
        __syncthreads();

        for (int kb = 0; kb < 256; kb += 32) {
            // K A-frags: A[m=key=kb+m31][k=d slice]; swizzled block read (8 lanes/16B col)
            int row0 = kb + m31;
            int swz  = (row0 >> 1) & 3;
            bf16x8 kfa = *(const bf16x8*)&Ks[row0 * 32 + (((0 + hi) ^ swz) << 3)];  // d  0..15
            bf16x8 kfb = *(const bf16x8*)&Ks[row0 * 32 + (((2 + hi) ^ swz) << 3)];  // d 16..31
            // V B-frags: B[n=d=m31][k=key slice]
            bf16x8 vf0 = *(const bf16x8*)&Vts[m31 * 264 + kb + hi * 8];        // keys kb+0..15
            bf16x8 vf1 = *(const bf16x8*)&Vts[m31 * 264 + kb + 16 + hi * 8];   // keys kb+16..31

            // Swapped QK^T: S[key=crow(r,hi)][q=m31], key_local = (r&3)+8*(r>>2)+4*hi
            f32x16 s = MFMA32(kfa, qf0, (f32x16)0.0f);
            s = MFMA32(kfb, qf1, s);

            float p[16];
#pragma unroll
            for (int r = 0; r < 16; ++r) p[r] = __builtin_amdgcn_exp2f(s[r]);

            float t01 = p[0] + p[1],   t23 = p[2] + p[3];
            float t45 = p[4] + p[5],   t67 = p[6] + p[7];
            float t89 = p[8] + p[9],   tab = p[10] + p[11];
            float tcd = p[12] + p[13], tef = p[14] + p[15];
            lsum += ((t01 + t23) + (t45 + t67)) + ((t89 + tab) + (tcd + tef));

            // PA frags in-register: keys {0,1},{2,3} own; rest via permlane32_swap
            unsigned c0 = cvtpk(p[0], p[1]);    // lo:{0,1}  hi:{4,5}
            unsigned c1 = cvtpk(p[2], p[3]);    // lo:{2,3}  hi:{6,7}
            unsigned c2 = cvtpk(p[4], p[5]);    // lo:{8,9}  hi:{12,13}
            unsigned c3 = cvtpk(p[6], p[7]);    // lo:{10,11} hi:{14,15}
            plswap(c0, c2);                     // c0: lo{0,1}/hi{8,9}   c2: lo{4,5}/hi{12,13}
            plswap(c1, c3);                     // c1: lo{2,3}/hi{10,11} c3: lo{6,7}/hi{14,15}
            i32x4 pw0; pw0[0] = c0; pw0[1] = c1; pw0[2] = c2; pw0[3] = c3;

            unsigned c4 = cvtpk(p[8], p[9]);
            unsigned c5 = cvtpk(p[10], p[11]);
            unsigned c6 = cvtpk(p[12], p[13]);
            unsigned c7 = cvtpk(p[14], p[15]);
            plswap(c4, c6);
            plswap(c5, c7);
            i32x4 pw1; pw1[0] = c4; pw1[1] = c5; pw1[2] = c6; pw1[3] = c7;

            o = MFMA32(__builtin_bit_cast(bf16x8, pw0), vf0, o);
            o = MFMA32(__builtin_bit_cast(bf16x8, pw1), vf1, o);
        }
    }

    // ---- epilogue: combine half-sums across lane^32, normalize, store f32
    float ls  = lsum + __shfl_xor(lsum, 32);
    float inv = 1.0f / ls;
    const size_t baseO = (size_t)b * 524288;
#pragma unroll
    for (int r = 0; r < 16; ++r) {
        int qw = (r & 3) + 8 * (r >> 2) + 4 * hi;     // local q row of o[r]
        float iv = __shfl(inv, qw);                   // inv for q=qw lives at lane qw
        int q  = q0w + qw;
        int lq = (q >> 3) * 64 + wb * 8 + (q & 7);
        out[baseO + (size_t)lq * 128 + chead + m31] = o[r] * iv;
    }
}

extern "C" void kernel_launch(void* const* d_in, const int* in_sizes, int n_in,
                              void* d_out, int out_size, void* d_ws, size_t ws_size,
                              hipStream_t stream) {
    const float* qkv = (const float*)d_in[0];
    float* out = (float*)d_out;
    lepe_attn_r13<<<dim3(1024), dim3(256), 0, stream>>>(qkv, out);
}